// Round 1
// baseline (138.788 us; speedup 1.0000x reference)
//
#include <hip/hip_runtime.h>
#include <hip/hip_bf16.h>
#include <cstdint>

#define B_ROWS 4096
#define DIM 1024
#define NN 8192  // 2*B

typedef int v4i __attribute__((ext_vector_type(4)));

__device__ __forceinline__ float wave_reduce_sum(float v) {
    v += __shfl_xor(v, 1);
    v += __shfl_xor(v, 2);
    v += __shfl_xor(v, 4);
    v += __shfl_xor(v, 8);
    v += __shfl_xor(v, 16);
    v += __shfl_xor(v, 32);
    return v;
}

__device__ __forceinline__ void gld_lds16(const void* g, void* l) {
    __builtin_amdgcn_global_load_lds(
        (__attribute__((address_space(1))) void*)(uintptr_t)g,
        (__attribute__((address_space(3))) void*)l, 16, 0, 0);
}

// Kernel 1: L2-normalize + positives, ONE WAVE PER ROW-PAIR. No LDS/barriers.
// rep is SIGNED i8: round(127 * normalized). |x̂| <= ~0.16 for N(0,1) data at
// D=1024, so no clamp needed; i32 MFMA accumulation is exact.
__global__ void norm_pos_kernel(const float* __restrict__ p1,
                                const float* __restrict__ p2,
                                signed char* __restrict__ rep,
                                float* __restrict__ pos) {
    const int wv = threadIdx.x >> 6, lane = threadIdx.x & 63;
    const int i = blockIdx.x * 4 + wv;  // 0..4095
    const float4* ap = (const float4*)(p1 + (size_t)i * DIM);
    const float4* bp = (const float4*)(p2 + (size_t)i * DIM);
    float4 a[4], b[4];
#pragma unroll
    for (int c = 0; c < 4; ++c) { a[c] = ap[lane + 64 * c]; b[c] = bp[lane + 64 * c]; }
    float s1 = 0.f, s2 = 0.f, dp = 0.f;
#pragma unroll
    for (int c = 0; c < 4; ++c) {
        s1 += a[c].x * a[c].x + a[c].y * a[c].y + a[c].z * a[c].z + a[c].w * a[c].w;
        s2 += b[c].x * b[c].x + b[c].y * b[c].y + b[c].z * b[c].z + b[c].w * b[c].w;
        dp += a[c].x * b[c].x + a[c].y * b[c].y + a[c].z * b[c].z + a[c].w * b[c].w;
    }
    s1 = wave_reduce_sum(s1);
    s2 = wave_reduce_sum(s2);
    dp = wave_reduce_sum(dp);
    const float sc1 = rsqrtf(s1) * 127.0f, sc2 = rsqrtf(s2) * 127.0f;
    char4* o1 = (char4*)(rep + (size_t)i * DIM);
    char4* o2 = (char4*)(rep + (size_t)(i + B_ROWS) * DIM);
#pragma unroll
    for (int c = 0; c < 4; ++c) {
        char4 u1, u2;
        u1.x = (signed char)__float2int_rn(a[c].x * sc1);
        u1.y = (signed char)__float2int_rn(a[c].y * sc1);
        u1.z = (signed char)__float2int_rn(a[c].z * sc1);
        u1.w = (signed char)__float2int_rn(a[c].w * sc1);
        u2.x = (signed char)__float2int_rn(b[c].x * sc2);
        u2.y = (signed char)__float2int_rn(b[c].y * sc2);
        u2.z = (signed char)__float2int_rn(b[c].z * sc2);
        u2.w = (signed char)__float2int_rn(b[c].w * sc2);
        o1[lane + 64 * c] = u1;
        o2[lane + 64 * c] = u2;
    }
    if (lane == 0) pos[i] = dp * rsqrtf(s1) * rsqrtf(s2);
}

// Kernel 2: symmetric fused GEMM in i8 (mfma_i32_16x16x64_i8). Upper-triangle
// tiles (rb<=cb), BK=64, 2x2 waves (64x64 each, 4x4 frags).
//
// R17 change vs R16-best: T3 "minimum 2-phase" pipeline + T1 XCD swizzle.
//  - Double-buffered LDS as FOUR separate __shared__ arrays (alias-analysis
//    clean: the prefetch global_load_lds writes target a different object
//    than the ds_reads, so the compiler has no reason to drain vmcnt early).
//  - Per K-tile: STAGE(next buffer) -> ds_read+MFMA(current) -> ONE
//    __syncthreads(). The barrier's implicit vmcnt(0) drain now lands AFTER
//    compute, so the ~500cy L3 latency hides under the ~330cy MFMA phase.
//    16-17 barriers total vs 32 before.
//  - bid = (orig%8)*260 + orig/8 (2080 = 8*260, bijective): consecutive
//    triangle bids share the A row-panel -> keep them on one XCD's L2.
//
// K-perm trick (unchanged): each lane reads its swizzled 16 B slot once;
// A-lane (m,q) and B-lane (n,q) hold the same 16 global-k bytes in the same
// order, so the HW pairs element j with element j at equal k — contraction
// invariant. Staging: thread t -> row t>>2, global 16B seg (t&3)^((row>>1)&3):
// per-quad one 64 B run (coalesced); LDS slot forced to t*16.
__global__ __launch_bounds__(256, 3) void gemm_kernel(const signed char* __restrict__ rep,
                                                      float* __restrict__ partial) {
    // XCD-chunked swizzle (8 XCDs, 2080 % 8 == 0 -> chunk = 260)
    const int bid0 = blockIdx.x;
    const int bid = (bid0 & 7) * 260 + (bid0 >> 3);
    // rb-major triangle decode: start(rb) = 64*rb - rb*(rb-1)/2
    int rb = (int)(64.5f - sqrtf(4160.25f - 2.0f * (float)bid));
    while (64 * (rb + 1) - (rb + 1) * rb / 2 <= bid) ++rb;
    while (64 * rb - rb * (rb - 1) / 2 > bid) --rb;
    const int cb = rb + (bid - (64 * rb - rb * (rb - 1) / 2));

    __shared__ __align__(16) signed char As0[8192];
    __shared__ __align__(16) signed char As1[8192];
    __shared__ __align__(16) signed char Bs0[8192];
    __shared__ __align__(16) signed char Bs1[8192];
    const int t = threadIdx.x;
    const int lane = t & 63;
    const int wv = t >> 6;     // 0..3
    const int wr = wv >> 1;    // wave row-half
    const int wc = wv & 1;     // wave col-half
    const int cm = lane & 15;  // frag m,n index
    const int q = lane >> 4;   // frag k-quarter

    // staging source
    const int sr = t >> 2;
    const int sg = (t & 3) ^ ((sr >> 1) & 3);
    const signed char* aS = rep + (size_t)(rb * 128 + sr) * DIM + sg * 16;
    const signed char* bS = rep + (size_t)(cb * 128 + sr) * DIM + sg * 16;

    // fragment read offsets (k-invariant): row cm within 64-row group, slot q^fsw
    const int fsw = (cm >> 1) & 3;
    const int aOff = wr * 4096 + cm * 64 + ((q ^ fsw) << 4);
    const int bOff = wc * 4096 + cm * 64 + ((q ^ fsw) << 4);

    v4i acc[4][4];
#pragma unroll
    for (int i = 0; i < 4; ++i)
#pragma unroll
        for (int j = 0; j < 4; ++j) acc[i][j] = (v4i){0, 0, 0, 0};

    auto STAGE = [&](signed char* Ad, signed char* Bd, int kk) {
        const signed char* a0 = aS + kk * 64;
        const signed char* b0 = bS + kk * 64;
        gld_lds16(a0, Ad + t * 16);                            // A rows 0..63
        gld_lds16(a0 + (size_t)64 * DIM, Ad + t * 16 + 4096);  // A rows 64..127
        gld_lds16(b0, Bd + t * 16);
        gld_lds16(b0 + (size_t)64 * DIM, Bd + t * 16 + 4096);
    };

    auto COMPUTE = [&](const signed char* Ab, const signed char* Bb) {
        v4i af[4], bf[4];
#pragma unroll
        for (int mi = 0; mi < 4; ++mi) af[mi] = *(const v4i*)(Ab + aOff + mi * 1024);
#pragma unroll
        for (int ni = 0; ni < 4; ++ni) bf[ni] = *(const v4i*)(Bb + bOff + ni * 1024);
#pragma unroll
        for (int mi = 0; mi < 4; ++mi)
#pragma unroll
            for (int ni = 0; ni < 4; ++ni)
                acc[mi][ni] = __builtin_amdgcn_mfma_i32_16x16x64_i8(
                    af[mi], bf[ni], acc[mi][ni], 0, 0, 0);
    };

    // Prologue: fill buffer 0, drain, then 2-phase pipeline (stage-ahead).
    STAGE(As0, Bs0, 0);
    __syncthreads();

    for (int kk = 0; kk < DIM / 64; kk += 2) {
        STAGE(As1, Bs1, kk + 1);   // prefetch next tile (other buffer)
        COMPUTE(As0, Bs0);         // compute current (loads in flight)
        __syncthreads();           // drain: buf1 ready, buf0 reads done
        if (kk + 2 < DIM / 64) STAGE(As0, Bs0, kk + 2);
        COMPUTE(As1, Bs1);
        if (kk + 2 < DIM / 64) __syncthreads();
    }

    // Epilogue. C/D layout: col = wc*64 + ni*16 + cm, row = wr*64 + mi*16 + q*4 + reg.
    // sim = acc / 127^2; exp(sim * 2). Row-partials -> slot 2*cb+wc;
    // transpose col-partials -> slot 2*rb+wr. Row r of block i receives
    // slots {2c,2c+1 : c>=i} ∪ {2c,2c+1 : c<i} = all 128, disjoint.
    const float esc = 2.0f / 16129.0f;  // (1/T) / 127^2
    float colsum[4];
#pragma unroll
    for (int ni = 0; ni < 4; ++ni) colsum[ni] = 0.f;

#pragma unroll
    for (int mi = 0; mi < 4; ++mi) {
#pragma unroll
        for (int reg = 0; reg < 4; ++reg) {
            const int grow = rb * 128 + wr * 64 + mi * 16 + (q << 2) + reg;
            float rs = 0.f;
#pragma unroll
            for (int ni = 0; ni < 4; ++ni) {
                const int gcol = cb * 128 + wc * 64 + ni * 16 + cm;
                const float e =
                    (grow == gcol) ? 0.f : __expf((float)acc[mi][ni][reg] * esc);
                rs += e;
                colsum[ni] += e;
            }
            rs += __shfl_xor(rs, 1);
            rs += __shfl_xor(rs, 2);
            rs += __shfl_xor(rs, 4);
            rs += __shfl_xor(rs, 8);
            if (cm == 0) partial[(size_t)(2 * cb + wc) * NN + grow] = rs;
        }
    }

    if (rb != cb) {
#pragma unroll
        for (int ni = 0; ni < 4; ++ni) {
            colsum[ni] += __shfl_xor(colsum[ni], 16);  // fold q
            colsum[ni] += __shfl_xor(colsum[ni], 32);
        }
        if (q == 0) {
#pragma unroll
            for (int ni = 0; ni < 4; ++ni)
                partial[(size_t)(2 * rb + wr) * NN + cb * 128 + wc * 64 + ni * 16 + cm] =
                    colsum[ni];
        }
    }
}

// Kernel 3: per-row denom -> per-row loss -> 64 block sums. 2 threads/row.
__global__ void reduce_rows_kernel(const float* __restrict__ partial,
                                   const float* __restrict__ pos,
                                   float* __restrict__ bsum) {
    const int g = blockIdx.x * 256 + threadIdx.x;  // 64 x 256 = 16384
    const int r = g >> 1;
    const int half = g & 1;
    float s0 = 0.f, s1 = 0.f, s2 = 0.f, s3 = 0.f;
    for (int kb = half * 64; kb < half * 64 + 64; kb += 4) {
        s0 += partial[(size_t)(kb + 0) * NN + r];
        s1 += partial[(size_t)(kb + 1) * NN + r];
        s2 += partial[(size_t)(kb + 2) * NN + r];
        s3 += partial[(size_t)(kb + 3) * NN + r];
    }
    float s = (s0 + s1) + (s2 + s3);
    s += __shfl_xor(s, 1);  // both lanes of the pair hold the full row sum
    float v = __logf(s) - pos[r & (B_ROWS - 1)] * 2.0f;  // counted twice; *0.5 below
    v = wave_reduce_sum(v);
    __shared__ float red[4];
    const int lane = threadIdx.x & 63, wv = threadIdx.x >> 6;
    if (lane == 0) red[wv] = v;
    __syncthreads();
    if (threadIdx.x == 0)
        bsum[blockIdx.x] = (red[0] + red[1] + red[2] + red[3]) * 0.5f;
}

// Kernel 4: final scalar
__global__ void final_kernel(const float* __restrict__ bsum,
                             float* __restrict__ out) {
    float s = bsum[threadIdx.x];
    s = wave_reduce_sum(s);
    if (threadIdx.x == 0) out[0] = s * (1.0f / NN);
}

extern "C" void kernel_launch(void* const* d_in, const int* in_sizes, int n_in,
                              void* d_out, int out_size, void* d_ws, size_t ws_size,
                              hipStream_t stream) {
    const float* p1 = (const float*)d_in[0];
    const float* p2 = (const float*)d_in[1];
    char* ws = (char*)d_ws;
    signed char* rep = (signed char*)ws;                      // 8 MiB (i8)
    float* partial = (float*)(ws + (size_t)8 * 1024 * 1024);  // 4 MiB (128 x 8192)
    float* pos = (float*)(ws + (size_t)12 * 1024 * 1024);     // 16 KiB
    float* bsum = (float*)(ws + (size_t)12 * 1024 * 1024 + 16384);  // 256 B
    float* out = (float*)d_out;

    norm_pos_kernel<<<1024, 256, 0, stream>>>(p1, p2, rep, pos);
    gemm_kernel<<<2080, 256, 0, stream>>>(rep, partial);
    reduce_rows_kernel<<<64, 256, 0, stream>>>(partial, pos, bsum);
    final_kernel<<<1, 64, 0, stream>>>(bsum, out);
}

// Round 2
// 137.529 us; speedup vs baseline: 1.0092x; 1.0092x over previous
//
#include <hip/hip_runtime.h>
#include <hip/hip_bf16.h>
#include <cstdint>

#define B_ROWS 4096
#define DIM 1024
#define NN 8192  // 2*B

typedef int v4i __attribute__((ext_vector_type(4)));

__device__ __forceinline__ float wave_reduce_sum(float v) {
    v += __shfl_xor(v, 1);
    v += __shfl_xor(v, 2);
    v += __shfl_xor(v, 4);
    v += __shfl_xor(v, 8);
    v += __shfl_xor(v, 16);
    v += __shfl_xor(v, 32);
    return v;
}

__device__ __forceinline__ void gld_lds16(const void* g, void* l) {
    __builtin_amdgcn_global_load_lds(
        (__attribute__((address_space(1))) void*)(uintptr_t)g,
        (__attribute__((address_space(3))) void*)l, 16, 0, 0);
}

// Kernel 1: L2-normalize + positives, ONE WAVE PER ROW-PAIR. No LDS/barriers.
// rep is SIGNED i8: round(127 * normalized). |x̂| <= ~0.16 for N(0,1) data at
// D=1024, so no clamp needed; i32 MFMA accumulation is exact.
__global__ void norm_pos_kernel(const float* __restrict__ p1,
                                const float* __restrict__ p2,
                                signed char* __restrict__ rep,
                                float* __restrict__ pos) {
    const int wv = threadIdx.x >> 6, lane = threadIdx.x & 63;
    const int i = blockIdx.x * 4 + wv;  // 0..4095
    const float4* ap = (const float4*)(p1 + (size_t)i * DIM);
    const float4* bp = (const float4*)(p2 + (size_t)i * DIM);
    float4 a[4], b[4];
#pragma unroll
    for (int c = 0; c < 4; ++c) { a[c] = ap[lane + 64 * c]; b[c] = bp[lane + 64 * c]; }
    float s1 = 0.f, s2 = 0.f, dp = 0.f;
#pragma unroll
    for (int c = 0; c < 4; ++c) {
        s1 += a[c].x * a[c].x + a[c].y * a[c].y + a[c].z * a[c].z + a[c].w * a[c].w;
        s2 += b[c].x * b[c].x + b[c].y * b[c].y + b[c].z * b[c].z + b[c].w * b[c].w;
        dp += a[c].x * b[c].x + a[c].y * b[c].y + a[c].z * b[c].z + a[c].w * b[c].w;
    }
    s1 = wave_reduce_sum(s1);
    s2 = wave_reduce_sum(s2);
    dp = wave_reduce_sum(dp);
    const float sc1 = rsqrtf(s1) * 127.0f, sc2 = rsqrtf(s2) * 127.0f;
    char4* o1 = (char4*)(rep + (size_t)i * DIM);
    char4* o2 = (char4*)(rep + (size_t)(i + B_ROWS) * DIM);
#pragma unroll
    for (int c = 0; c < 4; ++c) {
        char4 u1, u2;
        u1.x = (signed char)__float2int_rn(a[c].x * sc1);
        u1.y = (signed char)__float2int_rn(a[c].y * sc1);
        u1.z = (signed char)__float2int_rn(a[c].z * sc1);
        u1.w = (signed char)__float2int_rn(a[c].w * sc1);
        u2.x = (signed char)__float2int_rn(b[c].x * sc2);
        u2.y = (signed char)__float2int_rn(b[c].y * sc2);
        u2.z = (signed char)__float2int_rn(b[c].z * sc2);
        u2.w = (signed char)__float2int_rn(b[c].w * sc2);
        o1[lane + 64 * c] = u1;
        o2[lane + 64 * c] = u2;
    }
    if (lane == 0) pos[i] = dp * rsqrtf(s1) * rsqrtf(s2);
}

// Kernel 2: symmetric fused GEMM in i8 (mfma_i32_16x16x64_i8). Upper-triangle
// tiles (rb<=cb), BK=64, 2x2 waves (64x64 each, 4x4 frags).
//
// R18 change vs R17: T4 COUNTED vmcnt pipeline. R17's __syncthreads version
// was flat (56 us, MfmaUtil 24%) because __syncthreads drains vmcnt(0) at
// EVERY barrier — depth-1 lookahead with a full drain == no lookahead
// (m218: 8-phase-with-drain0 ~= 1-phase; the gain of pipelining IS the
// counted vmcnt). This version:
//  - 3 LDS buffers (48 KB total -> still exactly 3 blocks/CU), stage tile
//    kk+2 each iteration: loads span TWO compute phases (~650+ cy wave-time)
//    before being waited — covers even the ~900 cy HBM-miss latency.
//  - raw s_barrier + "s_waitcnt vmcnt(4)" (only the newest tile's 4 loads
//    may remain in flight). vmcnt never drains to 0 until the 2-iter tail.
//  - STAGE target at iter kk is the buffer read at iter kk-1: all waves are
//    provably past it (barrier), and the LDS write lands >=300 cy after the
//    barrier (global fetch first) — the m201-verified discipline for
//    ds_reads in flight across a raw barrier.
//  - fully unrolled kk loop so buffer selection (kk%3) is compile-time.
//
// K-perm trick (unchanged): each lane reads its swizzled 16 B slot once;
// A-lane (m,q) and B-lane (n,q) hold the same 16 global-k bytes in the same
// order, so the HW pairs element j with element j at equal k — contraction
// invariant. Staging: thread t -> row t>>2, global 16B seg (t&3)^((row>>1)&3):
// per-quad one 64 B run (coalesced); LDS slot forced to t*16.
__global__ __launch_bounds__(256, 3) void gemm_kernel(const signed char* __restrict__ rep,
                                                      float* __restrict__ partial) {
    // XCD-chunked swizzle (8 XCDs, 2080 % 8 == 0 -> chunk = 260)
    const int bid0 = blockIdx.x;
    const int bid = (bid0 & 7) * 260 + (bid0 >> 3);
    // rb-major triangle decode: start(rb) = 64*rb - rb*(rb-1)/2
    int rb = (int)(64.5f - sqrtf(4160.25f - 2.0f * (float)bid));
    while (64 * (rb + 1) - (rb + 1) * rb / 2 <= bid) ++rb;
    while (64 * rb - rb * (rb - 1) / 2 > bid) --rb;
    const int cb = rb + (bid - (64 * rb - rb * (rb - 1) / 2));

    __shared__ __align__(16) signed char As[3][8192];  // 24 KB
    __shared__ __align__(16) signed char Bs[3][8192];  // 24 KB
    const int t = threadIdx.x;
    const int lane = t & 63;
    const int wv = t >> 6;     // 0..3
    const int wr = wv >> 1;    // wave row-half
    const int wc = wv & 1;     // wave col-half
    const int cm = lane & 15;  // frag m,n index
    const int q = lane >> 4;   // frag k-quarter

    // staging source
    const int sr = t >> 2;
    const int sg = (t & 3) ^ ((sr >> 1) & 3);
    const signed char* aS = rep + (size_t)(rb * 128 + sr) * DIM + sg * 16;
    const signed char* bS = rep + (size_t)(cb * 128 + sr) * DIM + sg * 16;

    // fragment read offsets (k-invariant): row cm within 64-row group, slot q^fsw
    const int fsw = (cm >> 1) & 3;
    const int aOff = wr * 4096 + cm * 64 + ((q ^ fsw) << 4);
    const int bOff = wc * 4096 + cm * 64 + ((q ^ fsw) << 4);

    v4i acc[4][4];
#pragma unroll
    for (int i = 0; i < 4; ++i)
#pragma unroll
        for (int j = 0; j < 4; ++j) acc[i][j] = (v4i){0, 0, 0, 0};

    auto STAGE = [&](signed char* Ad, signed char* Bd, int kk) {
        const signed char* a0 = aS + kk * 64;
        const signed char* b0 = bS + kk * 64;
        gld_lds16(a0, Ad + t * 16);                            // A rows 0..63
        gld_lds16(a0 + (size_t)64 * DIM, Ad + t * 16 + 4096);  // A rows 64..127
        gld_lds16(b0, Bd + t * 16);
        gld_lds16(b0 + (size_t)64 * DIM, Bd + t * 16 + 4096);
    };

    auto COMPUTE = [&](const signed char* Ab, const signed char* Bb) {
        v4i af[4], bf[4];
#pragma unroll
        for (int mi = 0; mi < 4; ++mi) af[mi] = *(const v4i*)(Ab + aOff + mi * 1024);
#pragma unroll
        for (int ni = 0; ni < 4; ++ni) bf[ni] = *(const v4i*)(Bb + bOff + ni * 1024);
#pragma unroll
        for (int mi = 0; mi < 4; ++mi)
#pragma unroll
            for (int ni = 0; ni < 4; ++ni)
                acc[mi][ni] = __builtin_amdgcn_mfma_i32_16x16x64_i8(
                    af[mi], bf[ni], acc[mi][ni], 0, 0, 0);
    };

    // Prologue: stage tiles 0 and 1 (8 loads in flight).
    STAGE(As[0], Bs[0], 0);
    STAGE(As[1], Bs[1], 1);

    // Main loop, tiles 0..13: wait own tile (vmcnt(4): newest tile stays in
    // flight) -> barrier -> stage tile kk+2 -> compute tile kk.
#pragma unroll
    for (int kk = 0; kk < 14; ++kk) {
        asm volatile("s_waitcnt vmcnt(4)" ::: "memory");
        __builtin_amdgcn_s_barrier();
        STAGE(As[(kk + 2) % 3], Bs[(kk + 2) % 3], kk + 2);
        COMPUTE(As[kk % 3], Bs[kk % 3]);
    }
    // Tail: tiles 14 (one tile still in flight) and 15 (drain).
    asm volatile("s_waitcnt vmcnt(4)" ::: "memory");
    __builtin_amdgcn_s_barrier();
    COMPUTE(As[14 % 3], Bs[14 % 3]);
    asm volatile("s_waitcnt vmcnt(0)" ::: "memory");
    __builtin_amdgcn_s_barrier();
    COMPUTE(As[15 % 3], Bs[15 % 3]);

    // Epilogue. C/D layout: col = wc*64 + ni*16 + cm, row = wr*64 + mi*16 + q*4 + reg.
    // sim = acc / 127^2; exp(sim * 2). Row-partials -> slot 2*cb+wc;
    // transpose col-partials -> slot 2*rb+wr. Row r of block i receives
    // slots {2c,2c+1 : c>=i} ∪ {2c,2c+1 : c<i} = all 128, disjoint.
    const float esc = 2.0f / 16129.0f;  // (1/T) / 127^2
    float colsum[4];
#pragma unroll
    for (int ni = 0; ni < 4; ++ni) colsum[ni] = 0.f;

#pragma unroll
    for (int mi = 0; mi < 4; ++mi) {
#pragma unroll
        for (int reg = 0; reg < 4; ++reg) {
            const int grow = rb * 128 + wr * 64 + mi * 16 + (q << 2) + reg;
            float rs = 0.f;
#pragma unroll
            for (int ni = 0; ni < 4; ++ni) {
                const int gcol = cb * 128 + wc * 64 + ni * 16 + cm;
                const float e =
                    (grow == gcol) ? 0.f : __expf((float)acc[mi][ni][reg] * esc);
                rs += e;
                colsum[ni] += e;
            }
            rs += __shfl_xor(rs, 1);
            rs += __shfl_xor(rs, 2);
            rs += __shfl_xor(rs, 4);
            rs += __shfl_xor(rs, 8);
            if (cm == 0) partial[(size_t)(2 * cb + wc) * NN + grow] = rs;
        }
    }

    if (rb != cb) {
#pragma unroll
        for (int ni = 0; ni < 4; ++ni) {
            colsum[ni] += __shfl_xor(colsum[ni], 16);  // fold q
            colsum[ni] += __shfl_xor(colsum[ni], 32);
        }
        if (q == 0) {
#pragma unroll
            for (int ni = 0; ni < 4; ++ni)
                partial[(size_t)(2 * rb + wr) * NN + cb * 128 + wc * 64 + ni * 16 + cm] =
                    colsum[ni];
        }
    }
}

// Kernel 3: per-row denom -> per-row loss -> 64 block sums. 2 threads/row.
__global__ void reduce_rows_kernel(const float* __restrict__ partial,
                                   const float* __restrict__ pos,
                                   float* __restrict__ bsum) {
    const int g = blockIdx.x * 256 + threadIdx.x;  // 64 x 256 = 16384
    const int r = g >> 1;
    const int half = g & 1;
    float s0 = 0.f, s1 = 0.f, s2 = 0.f, s3 = 0.f;
    for (int kb = half * 64; kb < half * 64 + 64; kb += 4) {
        s0 += partial[(size_t)(kb + 0) * NN + r];
        s1 += partial[(size_t)(kb + 1) * NN + r];
        s2 += partial[(size_t)(kb + 2) * NN + r];
        s3 += partial[(size_t)(kb + 3) * NN + r];
    }
    float s = (s0 + s1) + (s2 + s3);
    s += __shfl_xor(s, 1);  // both lanes of the pair hold the full row sum
    float v = __logf(s) - pos[r & (B_ROWS - 1)] * 2.0f;  // counted twice; *0.5 below
    v = wave_reduce_sum(v);
    __shared__ float red[4];
    const int lane = threadIdx.x & 63, wv = threadIdx.x >> 6;
    if (lane == 0) red[wv] = v;
    __syncthreads();
    if (threadIdx.x == 0)
        bsum[blockIdx.x] = (red[0] + red[1] + red[2] + red[3]) * 0.5f;
}

// Kernel 4: final scalar
__global__ void final_kernel(const float* __restrict__ bsum,
                             float* __restrict__ out) {
    float s = bsum[threadIdx.x];
    s = wave_reduce_sum(s);
    if (threadIdx.x == 0) out[0] = s * (1.0f / NN);
}

extern "C" void kernel_launch(void* const* d_in, const int* in_sizes, int n_in,
                              void* d_out, int out_size, void* d_ws, size_t ws_size,
                              hipStream_t stream) {
    const float* p1 = (const float*)d_in[0];
    const float* p2 = (const float*)d_in[1];
    char* ws = (char*)d_ws;
    signed char* rep = (signed char*)ws;                      // 8 MiB (i8)
    float* partial = (float*)(ws + (size_t)8 * 1024 * 1024);  // 4 MiB (128 x 8192)
    float* pos = (float*)(ws + (size_t)12 * 1024 * 1024);     // 16 KiB
    float* bsum = (float*)(ws + (size_t)12 * 1024 * 1024 + 16384);  // 256 B
    float* out = (float*)d_out;

    norm_pos_kernel<<<1024, 256, 0, stream>>>(p1, p2, rep, pos);
    gemm_kernel<<<2080, 256, 0, stream>>>(rep, partial);
    reduce_rows_kernel<<<64, 256, 0, stream>>>(partial, pos, bsum);
    final_kernel<<<1, 64, 0, stream>>>(bsum, out);
}

// Round 3
// 137.096 us; speedup vs baseline: 1.0123x; 1.0032x over previous
//
#include <hip/hip_runtime.h>
#include <hip/hip_bf16.h>
#include <cstdint>

#define B_ROWS 4096
#define DIM 1024
#define NN 8192  // 2*B

typedef int v4i __attribute__((ext_vector_type(4)));

__device__ __forceinline__ float wave_reduce_sum(float v) {
    v += __shfl_xor(v, 1);
    v += __shfl_xor(v, 2);
    v += __shfl_xor(v, 4);
    v += __shfl_xor(v, 8);
    v += __shfl_xor(v, 16);
    v += __shfl_xor(v, 32);
    return v;
}

__device__ __forceinline__ void gld_lds16(const void* g, void* l) {
    __builtin_amdgcn_global_load_lds(
        (__attribute__((address_space(1))) void*)(uintptr_t)g,
        (__attribute__((address_space(3))) void*)l, 16, 0, 0);
}

// Kernel 1: L2-normalize + positives, ONE WAVE PER ROW-PAIR. No LDS/barriers.
// rep is SIGNED i8: round(127 * normalized). |x̂| <= ~0.16 for N(0,1) data at
// D=1024, so no clamp needed; i32 MFMA accumulation is exact.
__global__ void norm_pos_kernel(const float* __restrict__ p1,
                                const float* __restrict__ p2,
                                signed char* __restrict__ rep,
                                float* __restrict__ pos) {
    const int wv = threadIdx.x >> 6, lane = threadIdx.x & 63;
    const int i = blockIdx.x * 4 + wv;  // 0..4095
    const float4* ap = (const float4*)(p1 + (size_t)i * DIM);
    const float4* bp = (const float4*)(p2 + (size_t)i * DIM);
    float4 a[4], b[4];
#pragma unroll
    for (int c = 0; c < 4; ++c) { a[c] = ap[lane + 64 * c]; b[c] = bp[lane + 64 * c]; }
    float s1 = 0.f, s2 = 0.f, dp = 0.f;
#pragma unroll
    for (int c = 0; c < 4; ++c) {
        s1 += a[c].x * a[c].x + a[c].y * a[c].y + a[c].z * a[c].z + a[c].w * a[c].w;
        s2 += b[c].x * b[c].x + b[c].y * b[c].y + b[c].z * b[c].z + b[c].w * b[c].w;
        dp += a[c].x * b[c].x + a[c].y * b[c].y + a[c].z * b[c].z + a[c].w * b[c].w;
    }
    s1 = wave_reduce_sum(s1);
    s2 = wave_reduce_sum(s2);
    dp = wave_reduce_sum(dp);
    const float sc1 = rsqrtf(s1) * 127.0f, sc2 = rsqrtf(s2) * 127.0f;
    char4* o1 = (char4*)(rep + (size_t)i * DIM);
    char4* o2 = (char4*)(rep + (size_t)(i + B_ROWS) * DIM);
#pragma unroll
    for (int c = 0; c < 4; ++c) {
        char4 u1, u2;
        u1.x = (signed char)__float2int_rn(a[c].x * sc1);
        u1.y = (signed char)__float2int_rn(a[c].y * sc1);
        u1.z = (signed char)__float2int_rn(a[c].z * sc1);
        u1.w = (signed char)__float2int_rn(a[c].w * sc1);
        u2.x = (signed char)__float2int_rn(b[c].x * sc2);
        u2.y = (signed char)__float2int_rn(b[c].y * sc2);
        u2.z = (signed char)__float2int_rn(b[c].z * sc2);
        u2.w = (signed char)__float2int_rn(b[c].w * sc2);
        o1[lane + 64 * c] = u1;
        o2[lane + 64 * c] = u2;
    }
    if (lane == 0) pos[i] = dp * rsqrtf(s1) * rsqrtf(s2);
}

// Kernel 2 (R19): 256x128 rect tiles, 4 waves of 64x128 each.
//
// WHY: R0-R2 proved the gemm is schedule-INVARIANT (3 different
// barrier/vmcnt schedules all 56-59 us, MfmaUtil 24%). Pipe arithmetic: a
// 64x64 wave tile has register reuse 4.0 (8 KB ds_read -> 32 KB operand
// consumption) but feeding MFMA at peak needs reuse >= 4.7 (401 B/cy/CU
// demand vs LDS 85 B/cy measured) -> the old shape was DS-pipe-bound BY
// CONSTRUCTION. 64x128 wave tile: 12 ds_read feed 32 MFMA -> reuse 5.33,
// DS reads/MFMA -25%, staged bytes/MFMA -50%.
//
// Tiling: tiles (R,C): rows [256R,256R+256), cols [128C,128C+128), set
// = {C >= 2R}; 1056 tiles, start(R) = R*(65-R). Coverage: ordered pair
// (i,j) is covered by ROWSUM of its primary tile (i>>8, j>>7) when that
// tile is in the set; otherwise by COLSUM of the mirror tile (j>>8, i>>7)
// (always in set), predicated per-wave: include iff primary not in set,
// i.e. 2*rb+(wv>>1) < 2*(cb>>1) (wave-uniform: grow>>7 = 2rb+(wv>>1),
// gcol>>8 = cb>>1). Diagonal elements masked in-place (straddle tiles).
// Partial slots: rowsum -> slot cb (0..63); colsum -> slot 64+4*rb+wv
// (64..191), zero-written when predicate false so every existing slot is
// defined. Row j's valid slots = contiguous [2R, 68+4R), R=j>>8.
//
// K-perm trick (unchanged): lane (cm,q) reads LDS seg (q^fsw)... A-lane
// and B-lane hold the same 16 global-k bytes in the same order ->
// contraction invariant. Staging: thread t -> row t>>2, global seg
// (t&3)^((sr>>1)&3), LDS slot t*16 (gld_lds HW layout).
// Pipeline: 3 buffers, depth-2 prefetch, counted vmcnt(6) (6 loads/tile).
__global__ __launch_bounds__(256, 2) void gemm_kernel(const signed char* __restrict__ rep,
                                                      float* __restrict__ partial) {
    // XCD-chunked swizzle (1056 = 8*132, bijective)
    const int bid0 = blockIdx.x;
    const int bid = (bid0 & 7) * 132 + (bid0 >> 3);
    // decode: start(R) = R*(65-R), count 64-2R
    int rb = (int)((65.0f - sqrtf(4225.0f - 4.0f * (float)bid)) * 0.5f);
    while ((rb + 1) * (64 - rb) <= bid) ++rb;
    while (rb * (65 - rb) > bid) --rb;
    const int cb = 2 * rb + (bid - rb * (65 - rb));

    __shared__ __align__(16) signed char As[3][16384];  // 48 KB (256 rows x 64)
    __shared__ __align__(16) signed char Bs[3][8192];   // 24 KB (128 rows x 64)
    const int t = threadIdx.x;
    const int lane = t & 63;
    const int wv = t >> 6;     // 0..3: wave owns rows wv*64..wv*64+63 of the tile
    const int cm = lane & 15;  // frag m,n index
    const int q = lane >> 4;   // frag k-quarter

    // staging source
    const int sr = t >> 2;
    const int sg = (t & 3) ^ ((sr >> 1) & 3);
    const signed char* aS = rep + (size_t)(rb * 256 + sr) * DIM + sg * 16;
    const signed char* bS = rep + (size_t)(cb * 128 + sr) * DIM + sg * 16;

    // fragment read offsets (k-invariant)
    const int fsw = (cm >> 1) & 3;
    const int aOff = wv * 4096 + cm * 64 + ((q ^ fsw) << 4);
    const int bOff = cm * 64 + ((q ^ fsw) << 4);

    v4i acc[4][8];
#pragma unroll
    for (int i = 0; i < 4; ++i)
#pragma unroll
        for (int j = 0; j < 8; ++j) acc[i][j] = (v4i){0, 0, 0, 0};

    auto STAGE = [&](signed char* Ad, signed char* Bd, int kk) {
        const signed char* a0 = aS + kk * 64;
        const signed char* b0 = bS + kk * 64;
        gld_lds16(a0, Ad + t * 16);                              // A rows 0..63
        gld_lds16(a0 + (size_t)64 * DIM, Ad + t * 16 + 4096);    // 64..127
        gld_lds16(a0 + (size_t)128 * DIM, Ad + t * 16 + 8192);   // 128..191
        gld_lds16(a0 + (size_t)192 * DIM, Ad + t * 16 + 12288);  // 192..255
        gld_lds16(b0, Bd + t * 16);                              // B rows 0..63
        gld_lds16(b0 + (size_t)64 * DIM, Bd + t * 16 + 4096);    // 64..127
    };

    auto COMPUTE = [&](const signed char* Ab, const signed char* Bb) {
        v4i af[4], bf[8];
#pragma unroll
        for (int mi = 0; mi < 4; ++mi) af[mi] = *(const v4i*)(Ab + aOff + mi * 1024);
#pragma unroll
        for (int ni = 0; ni < 8; ++ni)
            bf[ni] = *(const v4i*)(Bb + bOff + (ni >> 2) * 4096 + (ni & 3) * 1024);
#pragma unroll
        for (int mi = 0; mi < 4; ++mi)
#pragma unroll
            for (int ni = 0; ni < 8; ++ni)
                acc[mi][ni] = __builtin_amdgcn_mfma_i32_16x16x64_i8(
                    af[mi], bf[ni], acc[mi][ni], 0, 0, 0);
    };

    // Prologue: stage tiles 0 and 1 (12 loads in flight).
    STAGE(As[0], Bs[0], 0);
    STAGE(As[1], Bs[1], 1);

#pragma unroll
    for (int kk = 0; kk < 14; ++kk) {
        asm volatile("s_waitcnt vmcnt(6)" ::: "memory");  // own tile done; newest in flight
        __builtin_amdgcn_s_barrier();
        STAGE(As[(kk + 2) % 3], Bs[(kk + 2) % 3], kk + 2);
        COMPUTE(As[kk % 3], Bs[kk % 3]);
    }
    asm volatile("s_waitcnt vmcnt(6)" ::: "memory");
    __builtin_amdgcn_s_barrier();
    COMPUTE(As[14 % 3], Bs[14 % 3]);
    asm volatile("s_waitcnt vmcnt(0)" ::: "memory");
    __builtin_amdgcn_s_barrier();
    COMPUTE(As[15 % 3], Bs[15 % 3]);

    // Epilogue. C/D: col = ni*16 + cm (tile-local), row = wv*64 + mi*16 + q*4 + reg.
    const float esc = 2.0f / 16129.0f;  // (1/T) / 127^2
    float colsum[8];
#pragma unroll
    for (int ni = 0; ni < 8; ++ni) colsum[ni] = 0.f;

#pragma unroll
    for (int mi = 0; mi < 4; ++mi) {
#pragma unroll
        for (int reg = 0; reg < 4; ++reg) {
            const int grow = rb * 256 + wv * 64 + mi * 16 + (q << 2) + reg;
            float rs = 0.f;
#pragma unroll
            for (int ni = 0; ni < 8; ++ni) {
                const int gcol = cb * 128 + ni * 16 + cm;
                const float e =
                    (grow == gcol) ? 0.f : __expf((float)acc[mi][ni][reg] * esc);
                rs += e;
                colsum[ni] += e;
            }
            rs += __shfl_xor(rs, 1);
            rs += __shfl_xor(rs, 2);
            rs += __shfl_xor(rs, 4);
            rs += __shfl_xor(rs, 8);
            if (cm == 0) partial[(size_t)cb * NN + grow] = rs;  // rowsum slot cb
        }
    }

    // colsum: include only pairs whose primary tile is NOT in the set.
    const bool pred = (2 * rb + (wv >> 1)) < 2 * (cb >> 1);
#pragma unroll
    for (int ni = 0; ni < 8; ++ni) {
        colsum[ni] += __shfl_xor(colsum[ni], 16);  // fold q (rows)
        colsum[ni] += __shfl_xor(colsum[ni], 32);
    }
    if (q == 0) {
#pragma unroll
        for (int ni = 0; ni < 8; ++ni)
            partial[(size_t)(64 + rb * 4 + wv) * NN + cb * 128 + ni * 16 + cm] =
                pred ? colsum[ni] : 0.f;
    }
}

// Kernel 3: per-row denom -> loss -> 64 block sums. 2 threads/row.
// Row j (R=j>>8) valid slots = contiguous [2R, 68+4R).
__global__ void reduce_rows_kernel(const float* __restrict__ partial,
                                   const float* __restrict__ pos,
                                   float* __restrict__ bsum) {
    const int g = blockIdx.x * 256 + threadIdx.x;  // 64 x 256 = 16384
    const int r = g >> 1;
    const int half = g & 1;
    const int R = r >> 8;
    const int s_end = 68 + 4 * R;
    float a0 = 0.f, a1 = 0.f;
    int s = 2 * R + half;
    for (; s + 2 < s_end; s += 4) {
        a0 += partial[(size_t)s * NN + r];
        a1 += partial[(size_t)(s + 2) * NN + r];
    }
    if (s < s_end) a0 += partial[(size_t)s * NN + r];
    float ssum = a0 + a1;
    ssum += __shfl_xor(ssum, 1);  // both lanes of the pair hold the full row sum
    float v = __logf(ssum) - pos[r & (B_ROWS - 1)] * 2.0f;  // counted twice; *0.5 below
    v = wave_reduce_sum(v);
    __shared__ float red[4];
    const int lane = threadIdx.x & 63, wv = threadIdx.x >> 6;
    if (lane == 0) red[wv] = v;
    __syncthreads();
    if (threadIdx.x == 0)
        bsum[blockIdx.x] = (red[0] + red[1] + red[2] + red[3]) * 0.5f;
}

// Kernel 4: final scalar
__global__ void final_kernel(const float* __restrict__ bsum,
                             float* __restrict__ out) {
    float s = bsum[threadIdx.x];
    s = wave_reduce_sum(s);
    if (threadIdx.x == 0) out[0] = s * (1.0f / NN);
}

extern "C" void kernel_launch(void* const* d_in, const int* in_sizes, int n_in,
                              void* d_out, int out_size, void* d_ws, size_t ws_size,
                              hipStream_t stream) {
    const float* p1 = (const float*)d_in[0];
    const float* p2 = (const float*)d_in[1];
    char* ws = (char*)d_ws;
    signed char* rep = (signed char*)ws;                      // 8 MiB (i8)
    float* partial = (float*)(ws + (size_t)8 * 1024 * 1024);  // 6 MiB (192 x 8192)
    float* pos = (float*)(ws + (size_t)14680064);             // 16 KiB
    float* bsum = (float*)(ws + (size_t)14680064 + 16384);    // 256 B
    float* out = (float*)d_out;

    norm_pos_kernel<<<1024, 256, 0, stream>>>(p1, p2, rep, pos);
    gemm_kernel<<<1056, 256, 0, stream>>>(rep, partial);
    reduce_rows_kernel<<<64, 256, 0, stream>>>(partial, pos, bsum);
    final_kernel<<<1, 64, 0, stream>>>(bsum, out);
}

// Round 4
// 135.456 us; speedup vs baseline: 1.0246x; 1.0121x over previous
//
#include <hip/hip_runtime.h>
#include <hip/hip_bf16.h>
#include <cstdint>

#define B_ROWS 4096
#define DIM 1024
#define NN 8192  // 2*B

typedef int v4i __attribute__((ext_vector_type(4)));

__device__ __forceinline__ float wave_reduce_sum(float v) {
    v += __shfl_xor(v, 1);
    v += __shfl_xor(v, 2);
    v += __shfl_xor(v, 4);
    v += __shfl_xor(v, 8);
    v += __shfl_xor(v, 16);
    v += __shfl_xor(v, 32);
    return v;
}

__device__ __forceinline__ void gld_lds16(const void* g, void* l) {
    __builtin_amdgcn_global_load_lds(
        (__attribute__((address_space(1))) void*)(uintptr_t)g,
        (__attribute__((address_space(3))) void*)l, 16, 0, 0);
}

// Kernel 1: L2-normalize + positives, ONE WAVE PER ROW-PAIR. No LDS/barriers.
// rep is SIGNED i8: round(127 * normalized). |x̂| <= ~0.16 for N(0,1) data at
// D=1024, so no clamp needed; i32 MFMA accumulation is exact.
__global__ void norm_pos_kernel(const float* __restrict__ p1,
                                const float* __restrict__ p2,
                                signed char* __restrict__ rep,
                                float* __restrict__ pos) {
    const int wv = threadIdx.x >> 6, lane = threadIdx.x & 63;
    const int i = blockIdx.x * 4 + wv;  // 0..4095
    const float4* ap = (const float4*)(p1 + (size_t)i * DIM);
    const float4* bp = (const float4*)(p2 + (size_t)i * DIM);
    float4 a[4], b[4];
#pragma unroll
    for (int c = 0; c < 4; ++c) { a[c] = ap[lane + 64 * c]; b[c] = bp[lane + 64 * c]; }
    float s1 = 0.f, s2 = 0.f, dp = 0.f;
#pragma unroll
    for (int c = 0; c < 4; ++c) {
        s1 += a[c].x * a[c].x + a[c].y * a[c].y + a[c].z * a[c].z + a[c].w * a[c].w;
        s2 += b[c].x * b[c].x + b[c].y * b[c].y + b[c].z * b[c].z + b[c].w * b[c].w;
        dp += a[c].x * b[c].x + a[c].y * b[c].y + a[c].z * b[c].z + a[c].w * b[c].w;
    }
    s1 = wave_reduce_sum(s1);
    s2 = wave_reduce_sum(s2);
    dp = wave_reduce_sum(dp);
    const float sc1 = rsqrtf(s1) * 127.0f, sc2 = rsqrtf(s2) * 127.0f;
    char4* o1 = (char4*)(rep + (size_t)i * DIM);
    char4* o2 = (char4*)(rep + (size_t)(i + B_ROWS) * DIM);
#pragma unroll
    for (int c = 0; c < 4; ++c) {
        char4 u1, u2;
        u1.x = (signed char)__float2int_rn(a[c].x * sc1);
        u1.y = (signed char)__float2int_rn(a[c].y * sc1);
        u1.z = (signed char)__float2int_rn(a[c].z * sc1);
        u1.w = (signed char)__float2int_rn(a[c].w * sc1);
        u2.x = (signed char)__float2int_rn(b[c].x * sc2);
        u2.y = (signed char)__float2int_rn(b[c].y * sc2);
        u2.z = (signed char)__float2int_rn(b[c].z * sc2);
        u2.w = (signed char)__float2int_rn(b[c].w * sc2);
        o1[lane + 64 * c] = u1;
        o2[lane + 64 * c] = u2;
    }
    if (lane == 0) pos[i] = dp * rsqrtf(s1) * rsqrtf(s2);
}

// Kernel 2 (R20): 256x128 rect tiles, 4 waves of 64x128, m201-style PHASED
// K-loop.
//
// WHY: R0-R3 proved the gemm is schedule-invariant at ~57-59 us across 4
// COARSE schedules (all "2-phase family": per K-tile, all ds_reads then all
// MFMAs, waves convoyed by barriers). Measured 18us-MFMA-floor / 58.6us =
// 30.7% — the exact m233 regime (2-phase = 607/2145 = 28% of MFMA-only;
// the ~72% gap is stage+vmcnt+barrier overhead that coarse variants can't
// remove). m196/m218: counted vmcnt (T4) and setprio (T5) only pay INSIDE
// the fine-grained phase interleave (T3) — R2 applied T4 without T3.
//
// This version: per K-tile, TWO m201-shaped phases:
//   { ds_read operand subtile | issue 3 of next-tile's 6 gld_lds
//     -> sched_barrier(0) -> s_barrier -> lgkmcnt(0)+sched_barrier(0)
//     -> setprio(1) -> 16 MFMA -> setprio(0) -> s_barrier }
// phase A: read af0-3,bf0-3, MFMA ni 0-3. phase B: read bf4-7, MFMA ni 4-7
// (af persists in registers). Counted vmcnt(6) ONCE per tile, placed
// BEFORE the tile-end barrier (per-wave vmcnt + barrier = block-wide
// guarantee that the next buffer is fully resident). 3 buffers, depth-2.
//
// Tiling/coverage/K-perm unchanged from R19 (see below).
// Tiles (R,C): rows [256R,256R+256), cols [128C,128C+128), set {C>=2R},
// 1056 tiles, start(R)=R*(65-R). Rowsum -> slot cb; colsum (predicate
// 2rb+(wv>>1) < 2(cb>>1), wave-uniform) -> slot 64+4rb+wv. Row j valid
// slots = [2R, 68+4R), R=j>>8. K-perm: lane (cm,q) reads seg (q^fsw);
// A-lane and B-lane hold the same 16 global-k bytes in the same order.
__global__ __launch_bounds__(256, 2) void gemm_kernel(const signed char* __restrict__ rep,
                                                      float* __restrict__ partial) {
    // XCD-chunked swizzle (1056 = 8*132, bijective)
    const int bid0 = blockIdx.x;
    const int bid = (bid0 & 7) * 132 + (bid0 >> 3);
    // decode: start(R) = R*(65-R), count 64-2R
    int rb = (int)((65.0f - sqrtf(4225.0f - 4.0f * (float)bid)) * 0.5f);
    while ((rb + 1) * (64 - rb) <= bid) ++rb;
    while (rb * (65 - rb) > bid) --rb;
    const int cb = 2 * rb + (bid - rb * (65 - rb));

    __shared__ __align__(16) signed char As[3][16384];  // 48 KB (256 rows x 64)
    __shared__ __align__(16) signed char Bs[3][8192];   // 24 KB (128 rows x 64)
    const int t = threadIdx.x;
    const int lane = t & 63;
    const int wv = t >> 6;     // 0..3: wave owns rows wv*64..wv*64+63 of the tile
    const int cm = lane & 15;  // frag m,n index
    const int q = lane >> 4;   // frag k-quarter

    // staging source
    const int sr = t >> 2;
    const int sg = (t & 3) ^ ((sr >> 1) & 3);
    const signed char* aS = rep + (size_t)(rb * 256 + sr) * DIM + sg * 16;
    const signed char* bS = rep + (size_t)(cb * 128 + sr) * DIM + sg * 16;

    // fragment read offsets (k-invariant)
    const int fsw = (cm >> 1) & 3;
    const int aOff = wv * 4096 + cm * 64 + ((q ^ fsw) << 4);
    const int bOff = cm * 64 + ((q ^ fsw) << 4);

    v4i acc[4][8];
#pragma unroll
    for (int i = 0; i < 4; ++i)
#pragma unroll
        for (int j = 0; j < 8; ++j) acc[i][j] = (v4i){0, 0, 0, 0};

    // half-STAGE: part 0 = A rows 0..191; part 1 = A rows 192..255 + B.
    auto STAGE_HALF = [&](signed char* Ad, signed char* Bd, int kk, int part) {
        const signed char* a0 = aS + kk * 64;
        const signed char* b0 = bS + kk * 64;
        if (part == 0) {
            gld_lds16(a0, Ad + t * 16);                             // A rows 0..63
            gld_lds16(a0 + (size_t)64 * DIM, Ad + t * 16 + 4096);   // 64..127
            gld_lds16(a0 + (size_t)128 * DIM, Ad + t * 16 + 8192);  // 128..191
        } else {
            gld_lds16(a0 + (size_t)192 * DIM, Ad + t * 16 + 12288); // 192..255
            gld_lds16(b0, Bd + t * 16);                             // B rows 0..63
            gld_lds16(b0 + (size_t)64 * DIM, Bd + t * 16 + 4096);   // 64..127
        }
    };

    // Prologue: stage tiles 0 and 1 (12 loads in flight); wait tile 0 (oldest
    // 6) then barrier -> buffer 0 fully resident for every wave.
    STAGE_HALF(As[0], Bs[0], 0, 0);
    STAGE_HALF(As[0], Bs[0], 0, 1);
    STAGE_HALF(As[1], Bs[1], 1, 0);
    STAGE_HALF(As[1], Bs[1], 1, 1);
    asm volatile("s_waitcnt vmcnt(6)" ::: "memory");
    __builtin_amdgcn_s_barrier();

#pragma unroll
    for (int kk = 0; kk < 16; ++kk) {
        const signed char* Ab = As[kk % 3];
        const signed char* Bb = Bs[kk % 3];
        signed char* Ast = As[(kk + 2) % 3];
        signed char* Bst = Bs[(kk + 2) % 3];
        const bool do_stage = (kk < 14);

        // ---- phase A: read af0-3 + bf0-3, stage half, MFMA ni 0-3 ----
        v4i af[4], bf[4];
#pragma unroll
        for (int mi = 0; mi < 4; ++mi) af[mi] = *(const v4i*)(Ab + aOff + mi * 1024);
#pragma unroll
        for (int ni = 0; ni < 4; ++ni) bf[ni] = *(const v4i*)(Bb + bOff + ni * 1024);
        if (do_stage) STAGE_HALF(Ast, Bst, kk + 2, 0);
        __builtin_amdgcn_sched_barrier(0);
        __builtin_amdgcn_s_barrier();
        asm volatile("s_waitcnt lgkmcnt(0)" ::: "memory");
        __builtin_amdgcn_sched_barrier(0);
        __builtin_amdgcn_s_setprio(1);
#pragma unroll
        for (int mi = 0; mi < 4; ++mi)
#pragma unroll
            for (int ni = 0; ni < 4; ++ni)
                acc[mi][ni] = __builtin_amdgcn_mfma_i32_16x16x64_i8(
                    af[mi], bf[ni], acc[mi][ni], 0, 0, 0);
        __builtin_amdgcn_s_setprio(0);
        __builtin_amdgcn_sched_barrier(0);
        __builtin_amdgcn_s_barrier();

        // ---- phase B: read bf4-7, stage other half, MFMA ni 4-7 ----
#pragma unroll
        for (int ni = 0; ni < 4; ++ni)
            bf[ni] = *(const v4i*)(Bb + bOff + 4096 + ni * 1024);
        if (do_stage) STAGE_HALF(Ast, Bst, kk + 2, 1);
        __builtin_amdgcn_sched_barrier(0);
        __builtin_amdgcn_s_barrier();
        asm volatile("s_waitcnt lgkmcnt(0)" ::: "memory");
        __builtin_amdgcn_sched_barrier(0);
        __builtin_amdgcn_s_setprio(1);
#pragma unroll
        for (int mi = 0; mi < 4; ++mi)
#pragma unroll
            for (int ni = 0; ni < 4; ++ni)
                acc[mi][4 + ni] = __builtin_amdgcn_mfma_i32_16x16x64_i8(
                    af[mi], bf[ni], acc[mi][4 + ni], 0, 0, 0);
        __builtin_amdgcn_s_setprio(0);
        __builtin_amdgcn_sched_barrier(0);

        // ---- tile end: counted wait for next buffer, then block-wide sync.
        if (kk < 14) {
            asm volatile("s_waitcnt vmcnt(6)" ::: "memory");  // tile kk+1 resident
            __builtin_amdgcn_s_barrier();
        } else if (kk == 14) {
            asm volatile("s_waitcnt vmcnt(0)" ::: "memory");  // tile 15 resident
            __builtin_amdgcn_s_barrier();
        }
    }

    // Epilogue. C/D: col = ni*16 + cm (tile-local), row = wv*64 + mi*16 + q*4 + reg.
    const float esc = 2.0f / 16129.0f;  // (1/T) / 127^2
    float colsum[8];
#pragma unroll
    for (int ni = 0; ni < 8; ++ni) colsum[ni] = 0.f;

#pragma unroll
    for (int mi = 0; mi < 4; ++mi) {
#pragma unroll
        for (int reg = 0; reg < 4; ++reg) {
            const int grow = rb * 256 + wv * 64 + mi * 16 + (q << 2) + reg;
            float rs = 0.f;
#pragma unroll
            for (int ni = 0; ni < 8; ++ni) {
                const int gcol = cb * 128 + ni * 16 + cm;
                const float e =
                    (grow == gcol) ? 0.f : __expf((float)acc[mi][ni][reg] * esc);
                rs += e;
                colsum[ni] += e;
            }
            rs += __shfl_xor(rs, 1);
            rs += __shfl_xor(rs, 2);
            rs += __shfl_xor(rs, 4);
            rs += __shfl_xor(rs, 8);
            if (cm == 0) partial[(size_t)cb * NN + grow] = rs;  // rowsum slot cb
        }
    }

    // colsum: include only pairs whose primary tile is NOT in the set.
    const bool pred = (2 * rb + (wv >> 1)) < 2 * (cb >> 1);
#pragma unroll
    for (int ni = 0; ni < 8; ++ni) {
        colsum[ni] += __shfl_xor(colsum[ni], 16);  // fold q (rows)
        colsum[ni] += __shfl_xor(colsum[ni], 32);
    }
    if (q == 0) {
#pragma unroll
        for (int ni = 0; ni < 8; ++ni)
            partial[(size_t)(64 + rb * 4 + wv) * NN + cb * 128 + ni * 16 + cm] =
                pred ? colsum[ni] : 0.f;
    }
}

// Kernel 3: per-row denom -> loss -> 64 block sums. 2 threads/row.
// Row j (R=j>>8) valid slots = contiguous [2R, 68+4R).
__global__ void reduce_rows_kernel(const float* __restrict__ partial,
                                   const float* __restrict__ pos,
                                   float* __restrict__ bsum) {
    const int g = blockIdx.x * 256 + threadIdx.x;  // 64 x 256 = 16384
    const int r = g >> 1;
    const int half = g & 1;
    const int R = r >> 8;
    const int s_end = 68 + 4 * R;
    float a0 = 0.f, a1 = 0.f;
    int s = 2 * R + half;
    for (; s + 2 < s_end; s += 4) {
        a0 += partial[(size_t)s * NN + r];
        a1 += partial[(size_t)(s + 2) * NN + r];
    }
    if (s < s_end) a0 += partial[(size_t)s * NN + r];
    float ssum = a0 + a1;
    ssum += __shfl_xor(ssum, 1);  // both lanes of the pair hold the full row sum
    float v = __logf(ssum) - pos[r & (B_ROWS - 1)] * 2.0f;  // counted twice; *0.5 below
    v = wave_reduce_sum(v);
    __shared__ float red[4];
    const int lane = threadIdx.x & 63, wv = threadIdx.x >> 6;
    if (lane == 0) red[wv] = v;
    __syncthreads();
    if (threadIdx.x == 0)
        bsum[blockIdx.x] = (red[0] + red[1] + red[2] + red[3]) * 0.5f;
}

// Kernel 4: final scalar
__global__ void final_kernel(const float* __restrict__ bsum,
                             float* __restrict__ out) {
    float s = bsum[threadIdx.x];
    s = wave_reduce_sum(s);
    if (threadIdx.x == 0) out[0] = s * (1.0f / NN);
}

extern "C" void kernel_launch(void* const* d_in, const int* in_sizes, int n_in,
                              void* d_out, int out_size, void* d_ws, size_t ws_size,
                              hipStream_t stream) {
    const float* p1 = (const float*)d_in[0];
    const float* p2 = (const float*)d_in[1];
    char* ws = (char*)d_ws;
    signed char* rep = (signed char*)ws;                      // 8 MiB (i8)
    float* partial = (float*)(ws + (size_t)8 * 1024 * 1024);  // 6 MiB (192 x 8192)
    float* pos = (float*)(ws + (size_t)14680064);             // 16 KiB
    float* bsum = (float*)(ws + (size_t)14680064 + 16384);    // 256 B
    float* out = (float*)d_out;

    norm_pos_kernel<<<1024, 256, 0, stream>>>(p1, p2, rep, pos);
    gemm_kernel<<<1056, 256, 0, stream>>>(rep, partial);
    reduce_rows_kernel<<<64, 256, 0, stream>>>(partial, pos, bsum);
    final_kernel<<<1, 64, 0, stream>>>(bsum, out);
}